// Round 2
// baseline (182.474 us; speedup 1.0000x reference)
//
#include <hip/hip_runtime.h>
#include <cstdint>
#include <cstddef>

// PConv via bf16 MFMA: out[b,m,c,w] = sum_k cat[b,m,k,c] * wn[b,m,k,w]
// cat = concat(gather(feat, inds), addf).  Per (b,m): D(67x16) = catT(67x16k) x wn(16k x16)
// -> five v_mfma_f32_16x16x32_bf16 tiles, K padded 16->32 with zeros.
// bf16 inputs / f32 accum: absmax ~0.1 << 0.6125 threshold.

namespace {
constexpr int B_    = 2;
constexpr int N_    = 50000;
constexpr int M_    = 50000;
constexpr int KNB   = 16;            // neighbors (contraction dim)
constexpr int CIN   = 64;
constexpr int CADD  = 3;
constexpr int CMID  = 16;
constexpr int COUT  = 67 * CMID;     // 1072
constexpr int PAIRS = B_ * M_;       // 100000
constexpr int ROWS  = 80;            // 67 used; tile 4 reads rows 64..79 (zero pad)
constexpr int RS    = 40;            // row stride in ushorts = 80 B (16B-aligned, bank-friendly)
constexpr int WPB   = 4;             // waves per block (wave-private LDS, no __syncthreads)
}

typedef short short8 __attribute__((ext_vector_type(8)));
typedef float f32x4  __attribute__((ext_vector_type(4)));

static __device__ __forceinline__ unsigned short f2bf(float x) {
  // round-to-nearest-even f32 -> bf16
  unsigned u = __builtin_bit_cast(unsigned, x);
  u = (u + 0x7FFFu + ((u >> 16) & 1u)) >> 16;
  return (unsigned short)u;
}

__global__ __launch_bounds__(256, 4)
void pconv_mfma(const float* __restrict__ feat,   // [B][N][64]
                const int*   __restrict__ inds,   // [B][M][16]
                const float* __restrict__ wnet,   // [B][M][16][16]
                const float* __restrict__ addf,   // [B][M][16][3]
                float* __restrict__ out)          // [B][M][1072]
{
  __shared__ unsigned short s_cat[WPB][ROWS * RS];

  const int lane = threadIdx.x & 63;
  const int wid  = threadIdx.x >> 6;
  unsigned short* catw = s_cat[wid];

  // One-time zero: k=16..31 halves, row pads, rows 67..79 stay zero forever,
  // so the K-padding of every MFMA contributes exactly 0.
  for (int i = lane; i < ROWS * RS; i += 64) catw[i] = 0;

  const int gw = (int)((blockIdx.x * blockDim.x + threadIdx.x) >> 6);
  const int nw = (int)((gridDim.x * blockDim.x) >> 6);

  const int rr = lane & 15;   // A row within tile / B col / D col
  const int g  = lane >> 4;   // k-group (8 k's per group)

  for (int p0 = gw; p0 < PAIRS; p0 += nw) {
    const int p = __builtin_amdgcn_readfirstlane(p0);   // wave-uniform -> SGPR addressing
    const int b = p / M_;
    const int*   __restrict__ idxp = inds + (size_t)p * KNB;
    const float* __restrict__ wnp  = wnet + (size_t)p * (KNB * CMID);
    const float* __restrict__ adp  = addf + (size_t)p * (KNB * CADD);
    float*       __restrict__ outp = out  + (size_t)p * COUT;
    const float* __restrict__ fb   = feat + (size_t)b * N_ * CIN;

    // ---- gather, inverted: lane owns channel c=lane; per k a coalesced 256B wave-load ----
    float fv[KNB];
    #pragma unroll
    for (int k = 0; k < KNB; ++k) {
      const int idx = idxp[k];                       // SGPR (s_load)
      fv[k] = fb[(size_t)idx * CIN + lane];
    }

    // ---- B fragment straight from global: lane<32 holds wn[k=8g+j][w=rr] ----
    float bw[8];
    if (lane < 32) {
      #pragma unroll
      for (int j = 0; j < 8; ++j)
        bw[j] = wnp[(g * 8 + j) * CMID + rr];
    } else {
      #pragma unroll
      for (int j = 0; j < 8; ++j) bw[j] = 0.f;       // k>=16 pad
    }

    // ---- additional features (48 values) ----
    float av = 0.f;
    if (lane < KNB * CADD) av = adp[lane];

    // ---- convert + stage cat column: catT[c=lane][k=0..15], k-contiguous bf16 ----
    short8 lo, hi;
    #pragma unroll
    for (int j = 0; j < 8; ++j) {
      lo[j] = (short)f2bf(fv[j]);
      hi[j] = (short)f2bf(fv[8 + j]);
    }
    *reinterpret_cast<short8*>(&catw[lane * RS])     = lo;   // k 0..7
    *reinterpret_cast<short8*>(&catw[lane * RS + 8]) = hi;   // k 8..15

    if (lane < KNB * CADD) {                         // rows 64..66 <- addf^T
      const int k  = lane / 3;
      const int c2 = lane - k * 3;
      catw[(CIN + c2) * RS + k] = f2bf(av);
    }

    short8 bfrag;
    #pragma unroll
    for (int j = 0; j < 8; ++j) bfrag[j] = (short)f2bf(bw[j]);

    // wave-synchronous: all 64 lanes' LDS writes drained before cross-lane reads.
    // DS ops are in-order per wave; "memory" clobber stops compiler reordering
    // of the ds_reads/ds_writes across this point (consumers are memory ops).
    asm volatile("s_waitcnt lgkmcnt(0)" ::: "memory");

    // ---- 5 MFMA tiles over c ----
    #pragma unroll
    for (int t = 0; t < 5; ++t) {
      // A: lane reads catT[16t + rr][8g .. 8g+7]  (16B aligned, zeros for k>=16)
      const short8 a =
          *reinterpret_cast<const short8*>(&catw[(t * 16 + rr) * RS + g * 8]);
      f32x4 acc = {0.f, 0.f, 0.f, 0.f};
      acc = __builtin_amdgcn_mfma_f32_16x16x32_bf16(a, bfrag, acc, 0, 0, 0);
      // D: row = 4g + r, col = rr  ->  out[(16t + 4g + r)*16 + rr]
      if (t < 4) {
        #pragma unroll
        for (int r = 0; r < 4; ++r)
          outp[(t * 16 + g * 4 + r) * CMID + rr] = acc[r];
      } else if (g == 0) {                            // only rows 64..66 are real
        #pragma unroll
        for (int r = 0; r < 3; ++r)
          outp[(CIN + r) * CMID + rr] = acc[r];
      }
    }
  }
}

extern "C" void kernel_launch(void* const* d_in, const int* in_sizes, int n_in,
                              void* d_out, int out_size, void* d_ws, size_t ws_size,
                              hipStream_t stream) {
  const float* feat = (const float*)d_in[0];
  const int*   inds = (const int*)d_in[1];
  const float* wnet = (const float*)d_in[2];
  const float* addf = (const float*)d_in[3];
  float* outp = (float*)d_out;

  dim3 grid(2048);
  dim3 block(256);
  hipLaunchKernelGGL(pconv_mfma, grid, block, 0, stream,
                     feat, inds, wnet, addf, outp);
}

// Round 5
// 173.676 us; speedup vs baseline: 1.0507x; 1.0507x over previous
//
#include <hip/hip_runtime.h>
#include <cstdint>
#include <cstddef>

// PConv, round 5 (round-3 design, resubmitted after two container-level infra
// failures on the same dead container; kernel itself never ran):
// LDS-free swapped-operand MFMA + 2-deep software pipeline.
// out[b,m,c,w] = sum_k cat[b,m,k,c] * wn[b,m,k,w],  cat = [gather(feat,inds) | addf]
// Per m: outT(16w x 67c) = wnT(16x16k) x cat(16k x 67c) -> 5 mfma_f32_16x16x32_bf16
// tiles (K padded to 32 with zeros kept in never-written lanes).
//   A-frag: lane(w=l&15, g=l>>4) holds wn[8g+j][w]          (g<2 loaded, g>=2 zero)
//   B-frag: lane(cc,g) holds feat[idx[8g+j]][16t+cc]        (direct-gather, no LDS)
//   D:      lane(cc,g) holds outT[4g+r][16t+cc] -> out[(16t+cc)*16 + 4g+r]
//           = one contiguous dwordx4 store per lane per tile (1KB/tile/wave).

namespace {
constexpr int B_   = 2;
constexpr int N_   = 50000;
constexpr int M_   = 50000;
constexpr int KNB  = 16;
constexpr int CIN  = 64;
constexpr int COUT = 67 * 16;      // 1072
constexpr int PAIRS = B_ * M_;     // 100000
}

typedef unsigned int u32;
typedef float  f32x4  __attribute__((ext_vector_type(4)));
typedef short  short8 __attribute__((ext_vector_type(8)));
typedef u32    u32x4  __attribute__((ext_vector_type(4)));

struct IdxS  { int v[16]; };                            // wave-uniform (SGPRs)
struct Stage { float bg[4][8]; float ad[8]; float wf[8]; };  // 48 f32 regs

// 8 x f32 -> bf16x8 by truncation: one v_perm_b32 per pair.
// (R2 RNE absmax was 0.125 vs threshold 0.6125; truncation expected ~0.25-0.3.)
static __device__ __forceinline__ short8 pack_bf8(const float* x) {
  u32x4 w;
  #pragma unroll
  for (int q = 0; q < 4; ++q)
    w[q] = __builtin_amdgcn_perm(__builtin_bit_cast(u32, x[2*q+1]),
                                 __builtin_bit_cast(u32, x[2*q]),
                                 0x07060302u);   // hi16(S0):hi16(S1)
  return __builtin_bit_cast(short8, w);
}

static __device__ __forceinline__ void load_idx(const int* __restrict__ idxp, IdxS& r) {
  #pragma unroll
  for (int j = 0; j < 16; ++j)
    r.v[j] = __builtin_amdgcn_readfirstlane(idxp[j]);
}

static __device__ __forceinline__ void load_stage(const float* __restrict__ fb,
                                                  const float* __restrict__ wnp,
                                                  const float* __restrict__ adp,
                                                  const IdxS& I, int lane, Stage& S) {
  const int cc = lane & 15;
  if (lane < 32) {
    const int hi = lane >> 4;                    // 0 or 1 (k-group)
    int rows[8];
    #pragma unroll
    for (int j = 0; j < 8; ++j) rows[j] = hi ? I.v[j + 8] : I.v[j];
    #pragma unroll
    for (int j = 0; j < 8; ++j) {
      const u32 rb = ((u32)rows[j]) << 6;        // row * 64 floats
      #pragma unroll
      for (int t = 0; t < 4; ++t)                // imm-offset siblings
        S.bg[t][j] = fb[rb + (u32)(t * 16 + cc)];
    }
    const u32 woff = (hi ? 128u : 0u) + (u32)cc; // wn[8hi+j][cc]
    #pragma unroll
    for (int j = 0; j < 8; ++j)
      S.wf[j] = __builtin_nontemporal_load(wnp + woff + j * 16);
    if (cc < 3) {                                // addf[8hi+j][cc]
      const u32 aoff = (hi ? 24u : 0u) + (u32)cc;
      #pragma unroll
      for (int j = 0; j < 8; ++j)
        S.ad[j] = __builtin_nontemporal_load(adp + aoff + j * 3);
    }
  }
}

static __device__ __forceinline__ void compute_store(const Stage& S,
                                                     float* __restrict__ op, int lane) {
  const int cc = lane & 15, g = lane >> 4;
  const int soff = cc * 16 + g * 4;              // (16t+cc)*16 + 4g, t via imm
  const short8 a = pack_bf8(S.wf);
  #pragma unroll
  for (int t = 0; t < 4; ++t) {
    const short8 b = pack_bf8(S.bg[t]);
    f32x4 acc = {0.f, 0.f, 0.f, 0.f};
    acc = __builtin_amdgcn_mfma_f32_16x16x32_bf16(a, b, acc, 0, 0, 0);
    __builtin_nontemporal_store(acc, reinterpret_cast<f32x4*>(op + soff + t * 256));
  }
  {
    const short8 b = pack_bf8(S.ad);
    f32x4 acc = {0.f, 0.f, 0.f, 0.f};
    acc = __builtin_amdgcn_mfma_f32_16x16x32_bf16(a, b, acc, 0, 0, 0);
    if (cc < 3)                                   // rows 64..66 only
      __builtin_nontemporal_store(acc, reinterpret_cast<f32x4*>(op + soff + 1024));
  }
}

__global__ __launch_bounds__(256, 3)
void pconv5(const float* __restrict__ feat, const int* __restrict__ inds,
            const float* __restrict__ wnet, const float* __restrict__ addf,
            float* __restrict__ out)
{
  const int lane = threadIdx.x & 63;
  const int gw = __builtin_amdgcn_readfirstlane(
      (int)((blockIdx.x * blockDim.x + threadIdx.x) >> 6));
  const int nw = (int)((gridDim.x * blockDim.x) >> 6);
  if (gw >= PAIRS) return;

  Stage sA = {}, sB = {};      // zero once: k>=16 pad lanes / cc>=3 stay 0 forever
  IdxS iA, iB;

  int p = gw;
  // prologue: idx(p) -> iA -> sA; idx(p+nw) staged in iB
  load_idx(inds + (size_t)p * KNB, iA);
  {
    const int p1 = (p + nw < PAIRS) ? (p + nw) : gw;   // clamp, not branch
    load_idx(inds + (size_t)p1 * KNB, iB);
  }
  {
    const int b = p / M_;
    load_stage(feat + (size_t)b * N_ * CIN, wnet + (size_t)p * 256,
               addf + (size_t)p * 48, iA, lane, sA);
  }

  while (true) {
    // PHASE A: sA has data(p); iB has idx(p+nw)
    {
      const int pf = (p + 2 * nw < PAIRS) ? (p + 2 * nw) : gw;
      load_idx(inds + (size_t)pf * KNB, iA);
      const int pn = (p + nw < PAIRS) ? (p + nw) : gw;
      const int bn = pn / M_;
      load_stage(feat + (size_t)bn * N_ * CIN, wnet + (size_t)pn * 256,
                 addf + (size_t)pn * 48, iB, lane, sB);
      compute_store(sA, out + (size_t)p * COUT, lane);
    }
    p += nw; if (p >= PAIRS) break;
    // PHASE B: sB has data(p); iA has idx(p+nw)
    {
      const int pf = (p + 2 * nw < PAIRS) ? (p + 2 * nw) : gw;
      load_idx(inds + (size_t)pf * KNB, iB);
      const int pn = (p + nw < PAIRS) ? (p + nw) : gw;
      const int bn = pn / M_;
      load_stage(feat + (size_t)bn * N_ * CIN, wnet + (size_t)pn * 256,
                 addf + (size_t)pn * 48, iA, lane, sA);
      compute_store(sB, out + (size_t)p * COUT, lane);
    }
    p += nw; if (p >= PAIRS) break;
  }
}

extern "C" void kernel_launch(void* const* d_in, const int* in_sizes, int n_in,
                              void* d_out, int out_size, void* d_ws, size_t ws_size,
                              hipStream_t stream) {
  const float* feat = (const float*)d_in[0];
  const int*   inds = (const int*)d_in[1];
  const float* wnet = (const float*)d_in[2];
  const float* addf = (const float*)d_in[3];
  float* outp = (float*)d_out;

  dim3 grid(2500);   // 10000 waves -> exactly 10 m-iterations per wave
  dim3 block(256);
  hipLaunchKernelGGL(pconv5, grid, block, 0, stream,
                     feat, inds, wnet, addf, outp);
}

// Round 6
// 167.421 us; speedup vs baseline: 1.0899x; 1.0374x over previous
//
#include <hip/hip_runtime.h>
#include <cstdint>
#include <cstddef>

// PConv, round 6: R5 pipeline + bf16 feat table in d_ws (halves gather HBM bytes).
// out[b,m,c,w] = sum_k cat[b,m,k,c] * wn[b,m,k,w],  cat = [gather(feat,inds) | addf]
// Per m: outT(16w x 67c) = wnT(16x16k) x cat(16k x 67c) -> 5 mfma_f32_16x16x32_bf16.
// Pre-pass: feat f32 [2*50000*64] -> bf16 table (RNE) in d_ws; main kernel gathers
// ushorts directly into the B-fragment (no pack). Fallback = exact R5 if ws too small.

namespace {
constexpr int B_   = 2;
constexpr int N_   = 50000;
constexpr int M_   = 50000;
constexpr int KNB  = 16;
constexpr int CIN  = 64;
constexpr int COUT = 67 * 16;      // 1072
constexpr int PAIRS = B_ * M_;     // 100000
constexpr int FELEMS = B_ * N_ * CIN;   // 6,400,000
}

typedef unsigned int u32;
typedef float  f32x4  __attribute__((ext_vector_type(4)));
typedef short  short8 __attribute__((ext_vector_type(8)));
typedef u32    u32x4  __attribute__((ext_vector_type(4)));
typedef u32    u32x2  __attribute__((ext_vector_type(2)));

struct IdxS   { int v[16]; };                                   // wave-uniform
struct StageT { unsigned short bg[4][8]; float ad[8]; float wf[8]; };
struct StageF { float bg[4][8]; float ad[8]; float wf[8]; };

// trunc-pack: 8 x f32 -> bf16x8, one v_perm per pair (R5-validated, absmax 0.25)
static __device__ __forceinline__ short8 pack_bf8(const float* x) {
  u32x4 w;
  #pragma unroll
  for (int q = 0; q < 4; ++q)
    w[q] = __builtin_amdgcn_perm(__builtin_bit_cast(u32, x[2*q+1]),
                                 __builtin_bit_cast(u32, x[2*q]),
                                 0x07060302u);
  return __builtin_bit_cast(short8, w);
}

static __device__ __forceinline__ u32 bfrne(float x) {
  u32 u = __builtin_bit_cast(u32, x);
  return (u + 0x7FFFu + ((u >> 16) & 1u)) >> 16;
}

// ---------------- pre-pass: f32 -> bf16 (RNE) table ----------------
__global__ __launch_bounds__(256)
void cvt_feat_bf16(const float* __restrict__ src, unsigned short* __restrict__ dst) {
  const int n4 = FELEMS / 4;
  int i = blockIdx.x * blockDim.x + threadIdx.x;
  const int stride = gridDim.x * blockDim.x;
  const f32x4* s4 = reinterpret_cast<const f32x4*>(src);
  for (; i < n4; i += stride) {
    f32x4 v = s4[i];
    u32x2 w;
    w[0] = bfrne(v[0]) | (bfrne(v[1]) << 16);
    w[1] = bfrne(v[2]) | (bfrne(v[3]) << 16);
    *reinterpret_cast<u32x2*>(dst + 4 * (size_t)i) = w;
  }
}

// ---------------- shared helpers ----------------
static __device__ __forceinline__ void load_idx(const int* __restrict__ idxp, IdxS& r) {
  #pragma unroll
  for (int j = 0; j < 16; ++j)
    r.v[j] = __builtin_amdgcn_readfirstlane(idxp[j]);
}

// ---------------- table (bf16) variant ----------------
static __device__ __forceinline__ void load_stage_t(const unsigned short* __restrict__ fb,
                                                    const float* __restrict__ wnp,
                                                    const float* __restrict__ adp,
                                                    const IdxS& I, int lane, StageT& S) {
  const int cc = lane & 15;
  if (lane < 32) {
    const int hi = lane >> 4;
    int rows[8];
    #pragma unroll
    for (int j = 0; j < 8; ++j) rows[j] = hi ? I.v[j + 8] : I.v[j];
    #pragma unroll
    for (int j = 0; j < 8; ++j) {
      const u32 rb = ((u32)rows[j]) << 6;        // row * 64 ushorts
      #pragma unroll
      for (int t = 0; t < 4; ++t)
        S.bg[t][j] = fb[rb + (u32)(t * 16 + cc)];   // 2B gather, bf16 already
    }
    const u32 woff = (hi ? 128u : 0u) + (u32)cc;
    #pragma unroll
    for (int j = 0; j < 8; ++j)
      S.wf[j] = __builtin_nontemporal_load(wnp + woff + j * 16);
    if (cc < 3) {
      const u32 aoff = (hi ? 24u : 0u) + (u32)cc;
      #pragma unroll
      for (int j = 0; j < 8; ++j)
        S.ad[j] = __builtin_nontemporal_load(adp + aoff + j * 3);
    }
  }
}

static __device__ __forceinline__ void compute_store_t(const StageT& S,
                                                       float* __restrict__ op, int lane) {
  const int cc = lane & 15, g = lane >> 4;
  const int soff = cc * 16 + g * 4;
  const short8 a = pack_bf8(S.wf);
  #pragma unroll
  for (int t = 0; t < 4; ++t) {
    short8 b;
    #pragma unroll
    for (int j = 0; j < 8; ++j) b[j] = (short)S.bg[t][j];
    f32x4 acc = {0.f, 0.f, 0.f, 0.f};
    acc = __builtin_amdgcn_mfma_f32_16x16x32_bf16(a, b, acc, 0, 0, 0);
    __builtin_nontemporal_store(acc, reinterpret_cast<f32x4*>(op + soff + t * 256));
  }
  {
    const short8 b = pack_bf8(S.ad);
    f32x4 acc = {0.f, 0.f, 0.f, 0.f};
    acc = __builtin_amdgcn_mfma_f32_16x16x32_bf16(a, b, acc, 0, 0, 0);
    if (cc < 3)
      __builtin_nontemporal_store(acc, reinterpret_cast<f32x4*>(op + soff + 1024));
  }
}

__global__ __launch_bounds__(256, 3)
void pconv6_tbl(const unsigned short* __restrict__ tbl, const int* __restrict__ inds,
                const float* __restrict__ wnet, const float* __restrict__ addf,
                float* __restrict__ out)
{
  const int lane = threadIdx.x & 63;
  const int gw = __builtin_amdgcn_readfirstlane(
      (int)((blockIdx.x * blockDim.x + threadIdx.x) >> 6));
  const int nw = (int)((gridDim.x * blockDim.x) >> 6);
  if (gw >= PAIRS) return;

  StageT sA = {}, sB = {};
  IdxS iA, iB;

  int p = gw;
  load_idx(inds + (size_t)p * KNB, iA);
  { const int p1 = (p + nw < PAIRS) ? (p + nw) : gw;
    load_idx(inds + (size_t)p1 * KNB, iB); }
  { const int b = p / M_;
    load_stage_t(tbl + (size_t)b * N_ * CIN, wnet + (size_t)p * 256,
                 addf + (size_t)p * 48, iA, lane, sA); }

  while (true) {
    {
      const int pf = (p + 2 * nw < PAIRS) ? (p + 2 * nw) : gw;
      load_idx(inds + (size_t)pf * KNB, iA);
      const int pn = (p + nw < PAIRS) ? (p + nw) : gw;
      const int bn = pn / M_;
      load_stage_t(tbl + (size_t)bn * N_ * CIN, wnet + (size_t)pn * 256,
                   addf + (size_t)pn * 48, iB, lane, sB);
      compute_store_t(sA, out + (size_t)p * COUT, lane);
    }
    p += nw; if (p >= PAIRS) break;
    {
      const int pf = (p + 2 * nw < PAIRS) ? (p + 2 * nw) : gw;
      load_idx(inds + (size_t)pf * KNB, iB);
      const int pn = (p + nw < PAIRS) ? (p + nw) : gw;
      const int bn = pn / M_;
      load_stage_t(tbl + (size_t)bn * N_ * CIN, wnet + (size_t)pn * 256,
                   addf + (size_t)pn * 48, iA, lane, sA);
      compute_store_t(sB, out + (size_t)p * COUT, lane);
    }
    p += nw; if (p >= PAIRS) break;
  }
}

// ---------------- fallback: exact R5 (f32 gather) ----------------
static __device__ __forceinline__ void load_stage_f(const float* __restrict__ fb,
                                                    const float* __restrict__ wnp,
                                                    const float* __restrict__ adp,
                                                    const IdxS& I, int lane, StageF& S) {
  const int cc = lane & 15;
  if (lane < 32) {
    const int hi = lane >> 4;
    int rows[8];
    #pragma unroll
    for (int j = 0; j < 8; ++j) rows[j] = hi ? I.v[j + 8] : I.v[j];
    #pragma unroll
    for (int j = 0; j < 8; ++j) {
      const u32 rb = ((u32)rows[j]) << 6;
      #pragma unroll
      for (int t = 0; t < 4; ++t)
        S.bg[t][j] = fb[rb + (u32)(t * 16 + cc)];
    }
    const u32 woff = (hi ? 128u : 0u) + (u32)cc;
    #pragma unroll
    for (int j = 0; j < 8; ++j)
      S.wf[j] = __builtin_nontemporal_load(wnp + woff + j * 16);
    if (cc < 3) {
      const u32 aoff = (hi ? 24u : 0u) + (u32)cc;
      #pragma unroll
      for (int j = 0; j < 8; ++j)
        S.ad[j] = __builtin_nontemporal_load(adp + aoff + j * 3);
    }
  }
}

static __device__ __forceinline__ void compute_store_f(const StageF& S,
                                                       float* __restrict__ op, int lane) {
  const int cc = lane & 15, g = lane >> 4;
  const int soff = cc * 16 + g * 4;
  const short8 a = pack_bf8(S.wf);
  #pragma unroll
  for (int t = 0; t < 4; ++t) {
    const short8 b = pack_bf8(S.bg[t]);
    f32x4 acc = {0.f, 0.f, 0.f, 0.f};
    acc = __builtin_amdgcn_mfma_f32_16x16x32_bf16(a, b, acc, 0, 0, 0);
    __builtin_nontemporal_store(acc, reinterpret_cast<f32x4*>(op + soff + t * 256));
  }
  {
    const short8 b = pack_bf8(S.ad);
    f32x4 acc = {0.f, 0.f, 0.f, 0.f};
    acc = __builtin_amdgcn_mfma_f32_16x16x32_bf16(a, b, acc, 0, 0, 0);
    if (cc < 3)
      __builtin_nontemporal_store(acc, reinterpret_cast<f32x4*>(op + soff + 1024));
  }
}

__global__ __launch_bounds__(256, 3)
void pconv6_f32(const float* __restrict__ feat, const int* __restrict__ inds,
                const float* __restrict__ wnet, const float* __restrict__ addf,
                float* __restrict__ out)
{
  const int lane = threadIdx.x & 63;
  const int gw = __builtin_amdgcn_readfirstlane(
      (int)((blockIdx.x * blockDim.x + threadIdx.x) >> 6));
  const int nw = (int)((gridDim.x * blockDim.x) >> 6);
  if (gw >= PAIRS) return;

  StageF sA = {}, sB = {};
  IdxS iA, iB;

  int p = gw;
  load_idx(inds + (size_t)p * KNB, iA);
  { const int p1 = (p + nw < PAIRS) ? (p + nw) : gw;
    load_idx(inds + (size_t)p1 * KNB, iB); }
  { const int b = p / M_;
    load_stage_f(feat + (size_t)b * N_ * CIN, wnet + (size_t)p * 256,
                 addf + (size_t)p * 48, iA, lane, sA); }

  while (true) {
    {
      const int pf = (p + 2 * nw < PAIRS) ? (p + 2 * nw) : gw;
      load_idx(inds + (size_t)pf * KNB, iA);
      const int pn = (p + nw < PAIRS) ? (p + nw) : gw;
      const int bn = pn / M_;
      load_stage_f(feat + (size_t)bn * N_ * CIN, wnet + (size_t)pn * 256,
                   addf + (size_t)pn * 48, iB, lane, sB);
      compute_store_f(sA, out + (size_t)p * COUT, lane);
    }
    p += nw; if (p >= PAIRS) break;
    {
      const int pf = (p + 2 * nw < PAIRS) ? (p + 2 * nw) : gw;
      load_idx(inds + (size_t)pf * KNB, iB);
      const int pn = (p + nw < PAIRS) ? (p + nw) : gw;
      const int bn = pn / M_;
      load_stage_f(feat + (size_t)bn * N_ * CIN, wnet + (size_t)pn * 256,
                   addf + (size_t)pn * 48, iA, lane, sA);
      compute_store_f(sB, out + (size_t)p * COUT, lane);
    }
    p += nw; if (p >= PAIRS) break;
  }
}

extern "C" void kernel_launch(void* const* d_in, const int* in_sizes, int n_in,
                              void* d_out, int out_size, void* d_ws, size_t ws_size,
                              hipStream_t stream) {
  const float* feat = (const float*)d_in[0];
  const int*   inds = (const int*)d_in[1];
  const float* wnet = (const float*)d_in[2];
  const float* addf = (const float*)d_in[3];
  float* outp = (float*)d_out;

  const size_t TBL_BYTES = (size_t)FELEMS * sizeof(unsigned short);  // 12.8 MB

  dim3 grid(2500), block(256);
  if (ws_size >= TBL_BYTES) {
    unsigned short* tbl = (unsigned short*)d_ws;
    hipLaunchKernelGGL(cvt_feat_bf16, dim3(2048), dim3(256), 0, stream, feat, tbl);
    hipLaunchKernelGGL(pconv6_tbl, grid, block, 0, stream,
                       tbl, inds, wnet, addf, outp);
  } else {
    hipLaunchKernelGGL(pconv6_f32, grid, block, 0, stream,
                       feat, inds, wnet, addf, outp);
  }
}

// Round 7
// 162.583 us; speedup vs baseline: 1.1223x; 1.0298x over previous
//
#include <hip/hip_runtime.h>
#include <cstdint>
#include <cstddef>

// PConv, round 7: kill the software pipeline, maximize TLP instead.
// Theory: R1/R2/R5/R6 all ~170-180us because each wave's m-iterations were
// latency-serialized (~1300-1900 cyc chain) with too few waves to cover.
// Now: 1 m per iteration, single 48-reg stage -> fits 128 VGPR cap ->
// launch_bounds(256,4) = 16 waves/CU; grid 4096 blocks. Only idx is
// prefetched (SGPRs, free). bf16 feat table in d_ws kept from R6.
//   outT(16w x 67c) = wnT(16x16k) x cat(16k x 67c), 5x mfma_f32_16x16x32_bf16.

namespace {
constexpr int B_   = 2;
constexpr int N_   = 50000;
constexpr int M_   = 50000;
constexpr int KNB  = 16;
constexpr int CIN  = 64;
constexpr int COUT = 67 * 16;      // 1072
constexpr int PAIRS = B_ * M_;     // 100000
constexpr int FELEMS = B_ * N_ * CIN;   // 6,400,000
}

typedef unsigned int u32;
typedef float  f32x4  __attribute__((ext_vector_type(4)));
typedef short  short8 __attribute__((ext_vector_type(8)));
typedef u32    u32x4  __attribute__((ext_vector_type(4)));
typedef u32    u32x2  __attribute__((ext_vector_type(2)));

struct IdxS   { int v[16]; };                                   // wave-uniform
struct StageT { unsigned short bg[4][8]; float ad[8]; float wf[8]; };
struct StageF { float bg[4][8]; float ad[8]; float wf[8]; };

// trunc-pack: 8 x f32 -> bf16x8, one v_perm per pair (R5/R6-validated)
static __device__ __forceinline__ short8 pack_bf8(const float* x) {
  u32x4 w;
  #pragma unroll
  for (int q = 0; q < 4; ++q)
    w[q] = __builtin_amdgcn_perm(__builtin_bit_cast(u32, x[2*q+1]),
                                 __builtin_bit_cast(u32, x[2*q]),
                                 0x07060302u);
  return __builtin_bit_cast(short8, w);
}

static __device__ __forceinline__ u32 bfrne(float x) {
  u32 u = __builtin_bit_cast(u32, x);
  return (u + 0x7FFFu + ((u >> 16) & 1u)) >> 16;
}

// ---------------- pre-pass: f32 -> bf16 (RNE) table ----------------
__global__ __launch_bounds__(256)
void cvt_feat_bf16(const float* __restrict__ src, unsigned short* __restrict__ dst) {
  const int n4 = FELEMS / 4;
  int i = blockIdx.x * blockDim.x + threadIdx.x;
  const int stride = gridDim.x * blockDim.x;
  const f32x4* s4 = reinterpret_cast<const f32x4*>(src);
  for (; i < n4; i += stride) {
    f32x4 v = s4[i];
    u32x2 w;
    w[0] = bfrne(v[0]) | (bfrne(v[1]) << 16);
    w[1] = bfrne(v[2]) | (bfrne(v[3]) << 16);
    *reinterpret_cast<u32x2*>(dst + 4 * (size_t)i) = w;
  }
}

// ---------------- helpers ----------------
static __device__ __forceinline__ void load_idx(const int* __restrict__ idxp, IdxS& r) {
  #pragma unroll
  for (int j = 0; j < 16; ++j)
    r.v[j] = __builtin_amdgcn_readfirstlane(idxp[j]);
}

static __device__ __forceinline__ void load_stage_t(const unsigned short* __restrict__ fb,
                                                    const float* __restrict__ wnp,
                                                    const float* __restrict__ adp,
                                                    const IdxS& I, int lane, StageT& S) {
  const int cc = lane & 15;
  if (lane < 32) {
    const int hi = lane >> 4;
    int rows[8];
    #pragma unroll
    for (int j = 0; j < 8; ++j) rows[j] = hi ? I.v[j + 8] : I.v[j];
    #pragma unroll
    for (int j = 0; j < 8; ++j) {
      const u32 rb = ((u32)rows[j]) << 6;        // row * 64 ushorts
      #pragma unroll
      for (int t = 0; t < 4; ++t)
        S.bg[t][j] = fb[rb + (u32)(t * 16 + cc)];
    }
    const u32 woff = (hi ? 128u : 0u) + (u32)cc;
    #pragma unroll
    for (int j = 0; j < 8; ++j)
      S.wf[j] = __builtin_nontemporal_load(wnp + woff + j * 16);
    if (cc < 3) {
      const u32 aoff = (hi ? 24u : 0u) + (u32)cc;
      #pragma unroll
      for (int j = 0; j < 8; ++j)
        S.ad[j] = __builtin_nontemporal_load(adp + aoff + j * 3);
    }
  }
}

static __device__ __forceinline__ void compute_store_t(const StageT& S,
                                                       float* __restrict__ op, int lane) {
  const int cc = lane & 15, g = lane >> 4;
  const int soff = cc * 16 + g * 4;
  const short8 a = pack_bf8(S.wf);
  #pragma unroll
  for (int t = 0; t < 4; ++t) {
    short8 b;
    #pragma unroll
    for (int j = 0; j < 8; ++j) b[j] = (short)S.bg[t][j];
    f32x4 acc = {0.f, 0.f, 0.f, 0.f};
    acc = __builtin_amdgcn_mfma_f32_16x16x32_bf16(a, b, acc, 0, 0, 0);
    __builtin_nontemporal_store(acc, reinterpret_cast<f32x4*>(op + soff + t * 256));
  }
  {
    const short8 b = pack_bf8(S.ad);
    f32x4 acc = {0.f, 0.f, 0.f, 0.f};
    acc = __builtin_amdgcn_mfma_f32_16x16x32_bf16(a, b, acc, 0, 0, 0);
    if (cc < 3)
      __builtin_nontemporal_store(acc, reinterpret_cast<f32x4*>(op + soff + 1024));
  }
}

// ---------------- main: no pipeline, 1 m per iteration, high TLP ----------------
__global__ __launch_bounds__(256, 4)
void pconv7_tbl(const unsigned short* __restrict__ tbl, const int* __restrict__ inds,
                const float* __restrict__ wnet, const float* __restrict__ addf,
                float* __restrict__ out)
{
  const int lane = threadIdx.x & 63;
  const int gw = __builtin_amdgcn_readfirstlane(
      (int)((blockIdx.x * blockDim.x + threadIdx.x) >> 6));
  const int nw = (int)((gridDim.x * blockDim.x) >> 6);
  if (gw >= PAIRS) return;

  IdxS iCur, iNext;
  load_idx(inds + (size_t)gw * KNB, iCur);

  for (int p = gw; p < PAIRS; p += nw) {
    const int pn = (p + nw < PAIRS) ? (p + nw) : gw;   // clamped idx prefetch (SGPRs)
    load_idx(inds + (size_t)pn * KNB, iNext);
    const int b = p / M_;
    StageT S = {};                                     // pad lanes stay zero
    load_stage_t(tbl + (size_t)b * N_ * CIN, wnet + (size_t)p * 256,
                 addf + (size_t)p * 48, iCur, lane, S);
    compute_store_t(S, out + (size_t)p * COUT, lane);
    #pragma unroll
    for (int j = 0; j < 16; ++j) iCur.v[j] = iNext.v[j];
  }
}

// ---------------- fallback (ws too small): same structure, f32 feat ----------------
static __device__ __forceinline__ void load_stage_f(const float* __restrict__ fb,
                                                    const float* __restrict__ wnp,
                                                    const float* __restrict__ adp,
                                                    const IdxS& I, int lane, StageF& S) {
  const int cc = lane & 15;
  if (lane < 32) {
    const int hi = lane >> 4;
    int rows[8];
    #pragma unroll
    for (int j = 0; j < 8; ++j) rows[j] = hi ? I.v[j + 8] : I.v[j];
    #pragma unroll
    for (int j = 0; j < 8; ++j) {
      const u32 rb = ((u32)rows[j]) << 6;
      #pragma unroll
      for (int t = 0; t < 4; ++t)
        S.bg[t][j] = fb[rb + (u32)(t * 16 + cc)];
    }
    const u32 woff = (hi ? 128u : 0u) + (u32)cc;
    #pragma unroll
    for (int j = 0; j < 8; ++j)
      S.wf[j] = __builtin_nontemporal_load(wnp + woff + j * 16);
    if (cc < 3) {
      const u32 aoff = (hi ? 24u : 0u) + (u32)cc;
      #pragma unroll
      for (int j = 0; j < 8; ++j)
        S.ad[j] = __builtin_nontemporal_load(adp + aoff + j * 3);
    }
  }
}

static __device__ __forceinline__ void compute_store_f(const StageF& S,
                                                       float* __restrict__ op, int lane) {
  const int cc = lane & 15, g = lane >> 4;
  const int soff = cc * 16 + g * 4;
  const short8 a = pack_bf8(S.wf);
  #pragma unroll
  for (int t = 0; t < 4; ++t) {
    const short8 b = pack_bf8(S.bg[t]);
    f32x4 acc = {0.f, 0.f, 0.f, 0.f};
    acc = __builtin_amdgcn_mfma_f32_16x16x32_bf16(a, b, acc, 0, 0, 0);
    __builtin_nontemporal_store(acc, reinterpret_cast<f32x4*>(op + soff + t * 256));
  }
  {
    const short8 b = pack_bf8(S.ad);
    f32x4 acc = {0.f, 0.f, 0.f, 0.f};
    acc = __builtin_amdgcn_mfma_f32_16x16x32_bf16(a, b, acc, 0, 0, 0);
    if (cc < 3)
      __builtin_nontemporal_store(acc, reinterpret_cast<f32x4*>(op + soff + 1024));
  }
}

__global__ __launch_bounds__(256, 4)
void pconv7_f32(const float* __restrict__ feat, const int* __restrict__ inds,
                const float* __restrict__ wnet, const float* __restrict__ addf,
                float* __restrict__ out)
{
  const int lane = threadIdx.x & 63;
  const int gw = __builtin_amdgcn_readfirstlane(
      (int)((blockIdx.x * blockDim.x + threadIdx.x) >> 6));
  const int nw = (int)((gridDim.x * blockDim.x) >> 6);
  if (gw >= PAIRS) return;

  IdxS iCur, iNext;
  load_idx(inds + (size_t)gw * KNB, iCur);

  for (int p = gw; p < PAIRS; p += nw) {
    const int pn = (p + nw < PAIRS) ? (p + nw) : gw;
    load_idx(inds + (size_t)pn * KNB, iNext);
    const int b = p / M_;
    StageF S = {};
    load_stage_f(feat + (size_t)b * N_ * CIN, wnet + (size_t)p * 256,
                 addf + (size_t)p * 48, iCur, lane, S);
    compute_store_f(S, out + (size_t)p * COUT, lane);
    #pragma unroll
    for (int j = 0; j < 16; ++j) iCur.v[j] = iNext.v[j];
  }
}

extern "C" void kernel_launch(void* const* d_in, const int* in_sizes, int n_in,
                              void* d_out, int out_size, void* d_ws, size_t ws_size,
                              hipStream_t stream) {
  const float* feat = (const float*)d_in[0];
  const int*   inds = (const int*)d_in[1];
  const float* wnet = (const float*)d_in[2];
  const float* addf = (const float*)d_in[3];
  float* outp = (float*)d_out;

  const size_t TBL_BYTES = (size_t)FELEMS * sizeof(unsigned short);  // 12.8 MB

  dim3 grid(4096), block(256);   // 16384 waves, ~6 m each; 4 blocks/CU resident
  if (ws_size >= TBL_BYTES) {
    unsigned short* tbl = (unsigned short*)d_ws;
    hipLaunchKernelGGL(cvt_feat_bf16, dim3(2048), dim3(256), 0, stream, feat, tbl);
    hipLaunchKernelGGL(pconv7_tbl, grid, block, 0, stream,
                       tbl, inds, wnet, addf, outp);
  } else {
    hipLaunchKernelGGL(pconv7_f32, grid, block, 0, stream,
                       feat, inds, wnet, addf, outp);
  }
}